// Round 1
// baseline (247.043 us; speedup 1.0000x reference)
//
#include <hip/hip_runtime.h>

// RollingBufferCache: B=4, H=8, S=512, D=128, BUF=4096, cur_len=6144 (>BUF)
// Output = concat(k_window, v_window), each [B,H,W,D] with W = min(cur_len,BUF) = 4096.
// No cache write-back needed: the reference returns only the gathered windows.
// For output row t: physical row p = (cur_len - W + t) % BUF.
// If p lies in the circular scatter range [(cur_len-S)%BUF, +S), source = new k/v chunk.

constexpr int Bc   = 4;
constexpr int Hc   = 8;
constexpr int Sc   = 512;
constexpr int Dc   = 128;
constexpr int BUFc = 4096;
constexpr int D4   = Dc / 4;          // 32 float4 per row
constexpr int Wc   = BUFc;            // window = min(6144, 4096) = 4096

__global__ __launch_bounds__(256)
void RollingBufferCache_kernel(const float4* __restrict__ kn,   // [B,H,S,D]
                               const float4* __restrict__ vn,   // [B,H,S,D]
                               const float4* __restrict__ kc,   // [B,H,BUF,D]
                               const float4* __restrict__ vc,   // [B,H,BUF,D]
                               const int*    __restrict__ curp,
                               float4*       __restrict__ out)  // [2,B,H,W,D]
{
    const int cur       = *curp;                       // uniform (s_load)
    const int window    = (cur < Wc) ? cur : Wc;       // = Wc here
    const int start_w   = cur - window;                // logical window start
    const int start_idx = (cur - Sc) & (BUFc - 1);     // scatter start (pow2 mod, neg-safe)

    const long half   = (long)Bc * Hc * Wc * D4;       // float4 per output tensor
    const long total  = 2 * half;
    const long stride = (long)gridDim.x * blockDim.x;

    for (long i = (long)blockIdx.x * blockDim.x + threadIdx.x; i < total; i += stride) {
        const bool is_v = (i >= half);
        const long j    = is_v ? (i - half) : i;

        const int d4 = (int)(j & (D4 - 1));            // j % 32
        const int t  = (int)((j >> 5) & (Wc - 1));     // (j/32) % 4096
        const int bh = (int)(j >> 17);                 // j / (32*4096)

        const int p   = (start_w + t) & (BUFc - 1);    // physical cache row
        const int off = (p - start_idx) & (BUFc - 1);  // position within scatter range?

        float4 val;
        if (off < Sc) {
            const float4* __restrict__ src = is_v ? vn : kn;
            val = src[((long)bh * Sc + off) * D4 + d4];
        } else {
            const float4* __restrict__ src = is_v ? vc : kc;
            val = src[((long)bh * BUFc + p) * D4 + d4];
        }
        out[i] = val;
    }
}

extern "C" void kernel_launch(void* const* d_in, const int* in_sizes, int n_in,
                              void* d_out, int out_size, void* d_ws, size_t ws_size,
                              hipStream_t stream) {
    const float4* kn   = (const float4*)d_in[0];
    const float4* vn   = (const float4*)d_in[1];
    const float4* kc   = (const float4*)d_in[2];
    const float4* vc   = (const float4*)d_in[3];
    const int*    curp = (const int*)  d_in[4];
    float4*       out  = (float4*)     d_out;

    // total float4 elements = out_size/4 = 8,388,608; 2048 blocks x 256 thr,
    // grid-stride: 16 float4 (256 B) per thread.
    RollingBufferCache_kernel<<<2048, 256, 0, stream>>>(kn, vn, kc, vc, curp, out);
}